// Round 4
// baseline (361.823 us; speedup 1.0000x reference)
//
#include <hip/hip_runtime.h>
#include <math.h>

#define MAX_SEQ   1024
#define NUM_HEADS 16
#define NUM_KV    4
#define HEAD_DIM  128
#define HIDDEN    2048
#define GROUPS    4
#define EPS       1e-6f
#define THETA     1000000.0f
#define SCALE     0.08838834764831845f  /* 1/sqrt(128) */

// workspace layout (float offsets)
#define QBUF  0                    // 32*16*128 = 65536  (q, post norm+rope)
#define KBUF  65536                // 32*4*128  = 16384  (k_new)
#define VBUF  81920                // 16384              (v_new)
#define AOUT  98304                // 32*2048 = 65536    (attention output)
#define ARENA 163840               // scratch arena (partials), reused:
                                   //  qkv: nsQ*32*3072, attn: 32*4*nsA*520, wo: nsW*32*2048

// ---------------- batched GEMV tile: 128 rows x 32 batches -----------------
// Each weight element enters exactly one block. LDS stride 68 breaks
// power-of-2 bank aliasing while keeping float4 alignment.
__device__ __forceinline__ void gemv_body(
    const float* __restrict__ W,   // row 0 at k-chunk base (row stride 2048)
    const float* __restrict__ X,   // batch 0 at k-chunk base (row stride 2048)
    float* __restrict__ part,      // [32 b][RS rows] partial for this ksplit
    int RS, int grow0, int nkt)
{
    __shared__ float wt[128 * 68];
    __shared__ float xs[32 * 68];
    const int tid = threadIdx.x;
    const int rg = tid >> 3, bg = tid & 7;

    float acc[4][4];
    #pragma unroll
    for (int i = 0; i < 4; ++i)
        #pragma unroll
        for (int j = 0; j < 4; ++j) acc[i][j] = 0.f;

    for (int kt = 0; kt < nkt; ++kt) {
        const float* Wk = W + kt * 64;
        const float* Xk = X + kt * 64;
        #pragma unroll
        for (int it = 0; it < 8; ++it) {
            const int linear = it * 256 + tid;
            const int r = linear >> 4, c4 = (linear & 15) * 4;
            *(float4*)&wt[r * 68 + c4] = *(const float4*)(Wk + (size_t)r * HIDDEN + c4);
        }
        #pragma unroll
        for (int it = 0; it < 2; ++it) {
            const int linear = it * 256 + tid;
            const int r = linear >> 4, c4 = (linear & 15) * 4;
            *(float4*)&xs[r * 68 + c4] = *(const float4*)(Xk + (size_t)r * HIDDEN + c4);
        }
        __syncthreads();

        #pragma unroll
        for (int kk = 0; kk < 64; kk += 4) {
            float4 a[4], bb[4];
            #pragma unroll
            for (int i = 0; i < 4; ++i) a[i]  = *(const float4*)&wt[(rg * 4 + i) * 68 + kk];
            #pragma unroll
            for (int j = 0; j < 4; ++j) bb[j] = *(const float4*)&xs[(bg * 4 + j) * 68 + kk];
            #pragma unroll
            for (int i = 0; i < 4; ++i)
                #pragma unroll
                for (int j = 0; j < 4; ++j)
                    acc[i][j] += a[i].x * bb[j].x + a[i].y * bb[j].y
                               + a[i].z * bb[j].z + a[i].w * bb[j].w;
        }
        __syncthreads();
    }

    #pragma unroll
    for (int j = 0; j < 4; ++j) {
        float4 o = make_float4(acc[0][j], acc[1][j], acc[2][j], acc[3][j]);
        *(float4*)(part + (size_t)(bg * 4 + j) * RS + grow0 + rg * 4) = o;
    }
}

// ---------------- Kernel 1a: QKV projection (partials) ---------------------
__global__ __launch_bounds__(256, 3) void gemv_qkv(
    const float* __restrict__ x, const float* __restrict__ wq,
    const float* __restrict__ wk, const float* __restrict__ wv,
    float* __restrict__ ws, int nsQ, int chunkK)
{
    const int mt = blockIdx.x / nsQ;         // 0..23
    const int ks = blockIdx.x % nsQ;
    const float* W;
    if (mt < 16)      W = wq + (size_t)mt * 128 * HIDDEN;
    else if (mt < 20) W = wk + (size_t)(mt - 16) * 128 * HIDDEN;
    else              W = wv + (size_t)(mt - 20) * 128 * HIDDEN;
    const int k0 = ks * chunkK;
    float* part = ws + ARENA + (size_t)ks * 32 * 3072;
    gemv_body(W + k0, x + k0, part, 3072, mt * 128, chunkK >> 6);
}

// ---------------- Kernel 1b: reduce partials + RMSNorm + RoPE --------------
__global__ __launch_bounds__(128) void qkv_post(
    const float* __restrict__ position, const float* __restrict__ qnw,
    const float* __restrict__ knw, float* __restrict__ ws, int nsQ)
{
    const int blk = blockIdx.x;
    const int b = blk / 24, h = blk % 24;    // h: 0-15 q, 16-19 k, 20-23 v
    const int d = threadIdx.x, lane = d & 63, wave = d >> 6;
    const int grow = h * 128 + d;

    float v = 0.f;
    for (int s = 0; s < nsQ; ++s)
        v += ws[ARENA + (size_t)s * 32 * 3072 + (size_t)b * 3072 + grow];

    if (h >= 20) {
        ws[VBUF + (size_t)(b * NUM_KV + (h - 20)) * HEAD_DIM + d] = v;
        return;
    }

    __shared__ float red[2];
    __shared__ float vl[128];
    vl[d] = v;
    float t2 = v * v;
    #pragma unroll
    for (int off = 32; off; off >>= 1) t2 += __shfl_xor(t2, off);
    if (lane == 0) red[wave] = t2;
    __syncthreads();

    if (d < 64) {
        const float norm = rsqrtf((red[0] + red[1]) * (1.0f / HEAD_DIM) + EPS);
        const float* nw = (h < 16) ? qnw : knw;
        float n1 = vl[d]      * norm * nw[d];
        float n2 = vl[d + 64] * norm * nw[d + 64];
        const float p = position[0];
        float invf = __powf(THETA, -(float)d * (1.0f / 64.0f));
        float f = p * invf, s, c;
        __sincosf(f, &s, &c);
        float* outp = (h < 16)
            ? ws + QBUF + (size_t)(b * NUM_HEADS + h) * HEAD_DIM
            : ws + KBUF + (size_t)(b * NUM_KV + (h - 16)) * HEAD_DIM;
        outp[d]      = n1 * c - n2 * s;
        outp[d + 64] = n2 * c + n1 * s;
    }
}

// ---------------- Kernel 2: flash-decode attention (split over seq) --------
__global__ __launch_bounds__(256) void attn_kernel(
    const float* __restrict__ kcache, const float* __restrict__ vcache,
    const float* __restrict__ position, float* __restrict__ ws, int nsA)
{
    const int blk = blockIdx.x;         // bk*nsA + split
    const int split = blk % nsA;
    const int bk = blk / nsA;           // b*4+kv
    const int tid = threadIdx.x, lane = tid & 63, wave = tid >> 6;
    const int half = lane >> 5, li = lane & 31;
    const int b = bk >> 2, kv = bk & 3;
    const int pos = (int)position[0];

    const int chunk = (pos + nsA) / nsA;     // ceil((pos+1)/nsA)
    const int s0 = split * chunk;
    const int s1 = min(s0 + chunk, pos + 1);

    const float* qb = ws + QBUF + ((size_t)b * NUM_HEADS + kv * GROUPS) * HEAD_DIM;
    float4 q4[4];
    #pragma unroll
    for (int g = 0; g < 4; ++g)
        q4[g] = ((const float4*)(qb + g * HEAD_DIM))[li];

    const float* kc = kcache + (size_t)bk * MAX_SEQ * HEAD_DIM;
    const float* vc = vcache + (size_t)bk * MAX_SEQ * HEAD_DIM;
    const float* knew = ws + KBUF + (size_t)bk * HEAD_DIM;
    const float* vnew = ws + VBUF + (size_t)bk * HEAD_DIM;

    float m[4], l[4]; float4 acc[4];
    #pragma unroll
    for (int g = 0; g < 4; ++g) {
        m[g] = -1e30f; l[g] = 0.f;
        acc[g] = make_float4(0.f, 0.f, 0.f, 0.f);
    }

    for (int t = s0 + wave * 2 + half; t < s1; t += 16) {
        const int tb = t + 8;
        const bool vb = (tb < s1);
        const int tbc = vb ? tb : t;
        const float4* kpa = (const float4*)((t   == pos) ? knew : kc + (size_t)t   * HEAD_DIM);
        const float4* kpb = (const float4*)((tbc == pos) ? knew : kc + (size_t)tbc * HEAD_DIM);
        const float4* vpa = (const float4*)((t   == pos) ? vnew : vc + (size_t)t   * HEAD_DIM);
        const float4* vpb = (const float4*)((tbc == pos) ? vnew : vc + (size_t)tbc * HEAD_DIM);
        float4 ka = kpa[li], kb = kpb[li];
        float4 va = vpa[li], vb4 = vpb[li];

        float sa[4], sb[4];
        #pragma unroll
        for (int g = 0; g < 4; ++g) {
            sa[g] = q4[g].x * ka.x + q4[g].y * ka.y + q4[g].z * ka.z + q4[g].w * ka.w;
            sb[g] = q4[g].x * kb.x + q4[g].y * kb.y + q4[g].z * kb.z + q4[g].w * kb.w;
        }
        #pragma unroll
        for (int off = 16; off; off >>= 1) {
            #pragma unroll
            for (int g = 0; g < 4; ++g) {
                sa[g] += __shfl_xor(sa[g], off);
                sb[g] += __shfl_xor(sb[g], off);
            }
        }
        #pragma unroll
        for (int g = 0; g < 4; ++g) {
            float sga = sa[g] * SCALE;
            float sgb = vb ? sb[g] * SCALE : -1e30f;
            float mn  = fmaxf(m[g], fmaxf(sga, sgb));
            float alpha = __expf(m[g] - mn);
            float pa = __expf(sga - mn);
            float pb = vb ? __expf(sgb - mn) : 0.f;
            l[g] = l[g] * alpha + pa + pb;
            acc[g].x = acc[g].x * alpha + pa * va.x + pb * vb4.x;
            acc[g].y = acc[g].y * alpha + pa * va.y + pb * vb4.y;
            acc[g].z = acc[g].z * alpha + pa * va.z + pb * vb4.z;
            acc[g].w = acc[g].w * alpha + pa * va.w + pb * vb4.w;
            m[g] = mn;
        }
    }

    __shared__ float sm[8][4], sl[8][4];
    __shared__ float4 sacc[8][4][32];
    const int st = wave * 2 + half;
    #pragma unroll
    for (int g = 0; g < 4; ++g) {
        if (li == 0) { sm[st][g] = m[g]; sl[st][g] = l[g]; }
        sacc[st][g][li] = acc[g];
    }
    __syncthreads();

    float* part = ws + ARENA + (size_t)blk * 4 * 130;
    if (tid < HEAD_DIM) {
        const int d = tid;
        #pragma unroll
        for (int g = 0; g < 4; ++g) {
            float M = -1e30f;
            #pragma unroll
            for (int s = 0; s < 8; ++s) M = fmaxf(M, sm[s][g]);
            float L = 0.f, A = 0.f;
            #pragma unroll
            for (int s = 0; s < 8; ++s) {
                float e = __expf(sm[s][g] - M);
                L += sl[s][g] * e;
                A += ((const float*)&sacc[s][g][0])[d] * e;
            }
            part[g * 130 + d] = A;
            if (d == 0) { part[g * 130 + 128] = M; part[g * 130 + 129] = L; }
        }
    }
}

// ---------------- Kernel 3: combine split partials -> attn_out -------------
__global__ __launch_bounds__(128) void comb_kernel(float* __restrict__ ws, int nsA)
{
    const int blk = blockIdx.x;         // b*16 + h
    const int b = blk >> 4, h = blk & 15;
    const int kv = h >> 2, g = h & 3;
    const int d = threadIdx.x;
    const float* base = ws + ARENA + (size_t)(b * NUM_KV + kv) * nsA * 520 + g * 130;

    float M = -1e30f;
    for (int s = 0; s < nsA; ++s) M = fmaxf(M, base[(size_t)s * 520 + 128]);
    float L = 0.f, A = 0.f;
    for (int s = 0; s < nsA; ++s) {
        float e = __expf(base[(size_t)s * 520 + 128] - M);
        L += base[(size_t)s * 520 + 129] * e;
        A += base[(size_t)s * 520 + d] * e;
    }
    ws[AOUT + (size_t)b * HIDDEN + h * HEAD_DIM + d] = A / L;
}

// ---------------- Kernel 4a: output projection (partials) ------------------
__global__ __launch_bounds__(256, 3) void gemv_wo(
    const float* __restrict__ wo, float* __restrict__ ws, int nsW, int chunkK)
{
    const int mt = blockIdx.x / nsW;         // 0..15
    const int ks = blockIdx.x % nsW;
    const int k0 = ks * chunkK;
    float* part = ws + ARENA + (size_t)ks * 32 * 2048;
    gemv_body(wo + (size_t)mt * 128 * HIDDEN + k0, ws + AOUT + k0,
              part, 2048, mt * 128, chunkK >> 6);
}

// ---------------- Kernel 4b: reduce wo partials -> out ---------------------
__global__ __launch_bounds__(256) void ocomb(
    const float* __restrict__ ws, float* __restrict__ out, int nsW)
{
    const int idx = blockIdx.x * 256 + threadIdx.x;   // 0..16383
    const int b = idx >> 9, r4 = (idx & 511) * 4;
    float4 s = make_float4(0.f, 0.f, 0.f, 0.f);
    for (int k = 0; k < nsW; ++k) {
        float4 t = *(const float4*)(ws + ARENA + (size_t)k * 32 * 2048 + (size_t)b * 2048 + r4);
        s.x += t.x; s.y += t.y; s.z += t.z; s.w += t.w;
    }
    *(float4*)(out + (size_t)b * HIDDEN + r4) = s;
}

extern "C" void kernel_launch(void* const* d_in, const int* in_sizes, int n_in,
                              void* d_out, int out_size, void* d_ws, size_t ws_size,
                              hipStream_t stream) {
    const float* x        = (const float*)d_in[0];
    const float* position = (const float*)d_in[1];
    const float* kcache   = (const float*)d_in[3];
    const float* vcache   = (const float*)d_in[4];
    const float* wq       = (const float*)d_in[6];
    const float* wk       = (const float*)d_in[7];
    const float* wv       = (const float*)d_in[8];
    const float* wo       = (const float*)d_in[9];
    const float* qnw      = (const float*)d_in[10];
    const float* knw      = (const float*)d_in[11];
    float* ws  = (float*)d_ws;
    float* out = (float*)d_out;

    // ws_size is fixed across calls -> this branch is deterministic.
    const size_t need32 = (size_t)(ARENA + 32 * 32 * 3072) * sizeof(float);  // 13.3 MB
    int nsQ, nsA, nsW;
    if (ws_size >= need32) { nsQ = 32; nsA = 16; nsW = 32; }
    else                   { nsQ = 8;  nsA = 8;  nsW = 16; }   // R3 sizes (4.85 MB)

    gemv_qkv<<<24 * nsQ, 256, 0, stream>>>(x, wq, wk, wv, ws, nsQ, HIDDEN / nsQ);
    qkv_post<<<32 * 24, 128, 0, stream>>>(position, qnw, knw, ws, nsQ);
    attn_kernel<<<32 * NUM_KV * nsA, 256, 0, stream>>>(kcache, vcache, position, ws, nsA);
    comb_kernel<<<32 * NUM_HEADS, 128, 0, stream>>>(ws, nsA);
    gemv_wo<<<16 * nsW, 256, 0, stream>>>(wo, ws, nsW, HIDDEN / nsW);
    ocomb<<<64, 256, 0, stream>>>(ws, out, nsW);
}

// Round 5
// 225.103 us; speedup vs baseline: 1.6074x; 1.6074x over previous
//
#include <hip/hip_runtime.h>
#include <math.h>

#define MAX_SEQ   1024
#define NUM_HEADS 16
#define NUM_KV    4
#define HEAD_DIM  128
#define HIDDEN    2048
#define GROUPS    4
#define EPS       1e-6f
#define THETA     1000000.0f
#define SCALE     0.08838834764831845f  /* 1/sqrt(128) */
#define NSPLIT    8
#define KT        32

// workspace layout (float offsets)
#define QBUF  0                    // 32*16*128 = 65536  (q, post norm+rope)
#define KBUF  65536                // 32*4*128  = 16384  (k_new)
#define VBUF  81920                // 16384              (v_new)
#define AOUT  98304                // 32*2048 = 65536    (attention output)
#define ARENA 163840               // partials arena (reused sequentially):
                                   //  qkv: 8*32*3072=786432; attn: 1024*520=532480; wo: 16*32*2048=1048576
// total ws = 163840 + 1048576 = 1212416 floats = 4.85 MB (same as R3)

// ------- batched GEMV tile: 128 rows x 32 batches, double-buffered ---------
// Each weight element enters exactly one block (weight-read-once).
// Thread (rg=tid>>3, bg=tid&7) computes rows {rg+32i} x batches {bg+8j}:
// with LDS row stride 36, read banks are 4*rg / 4*bg -> 8 distinct groups,
// conflict-free (the old {4rg+i} mapping aliased to 2 groups).
__device__ __forceinline__ void gemv_body(
    const float* __restrict__ W,   // row 0 at k-chunk base (row stride 2048)
    const float* __restrict__ X,   // batch 0 at k-chunk base (row stride 2048)
    float* __restrict__ part,      // [32 b][RS rows] partial for this ksplit
    int RS, int grow0, int nkt)
{
    __shared__ float wt[2][128 * 36];
    __shared__ float xs[2][32 * 36];
    const int tid = threadIdx.x;
    const int rg = tid >> 3, bg = tid & 7;
    const int sr = tid >> 3, sc = (tid & 7) * 4;   // staging coords

    float4 wreg[4];
    float4 xreg;

    // stage tile kt into registers (global loads, coalesced 32B/row-segment)
    #define ISSUE(kt_) do {                                                   \
        const float* Wk_ = W + (kt_) * KT;                                    \
        const float* Xk_ = X + (kt_) * KT;                                    \
        _Pragma("unroll")                                                     \
        for (int it = 0; it < 4; ++it) {                                      \
            const int lin = it * 256 + tid;                                   \
            const int r_ = lin >> 3, c_ = (lin & 7) * 4;                      \
            wreg[it] = *(const float4*)(Wk_ + (size_t)r_ * HIDDEN + c_);      \
        }                                                                     \
        xreg = *(const float4*)(Xk_ + (size_t)sr * HIDDEN + sc);              \
    } while (0)

    #define COMMIT(buf_) do {                                                 \
        _Pragma("unroll")                                                     \
        for (int it = 0; it < 4; ++it) {                                      \
            const int lin = it * 256 + tid;                                   \
            const int r_ = lin >> 3, c_ = (lin & 7) * 4;                      \
            *(float4*)&wt[buf_][r_ * 36 + c_] = wreg[it];                     \
        }                                                                     \
        *(float4*)&xs[buf_][sr * 36 + sc] = xreg;                             \
    } while (0)

    float acc[4][4];
    #pragma unroll
    for (int i = 0; i < 4; ++i)
        #pragma unroll
        for (int j = 0; j < 4; ++j) acc[i][j] = 0.f;

    ISSUE(0); COMMIT(0);
    __syncthreads();

    for (int kt = 0; kt < nkt; ++kt) {
        const int cur = kt & 1, nxt = cur ^ 1;
        if (kt + 1 < nkt) ISSUE(kt + 1);      // loads in flight during compute

        #pragma unroll
        for (int kk = 0; kk < KT; kk += 4) {
            float4 a[4], bb[4];
            #pragma unroll
            for (int i = 0; i < 4; ++i)
                a[i] = *(const float4*)&wt[cur][(i * 32 + rg) * 36 + kk];
            #pragma unroll
            for (int j = 0; j < 4; ++j)
                bb[j] = *(const float4*)&xs[cur][(j * 8 + bg) * 36 + kk];
            #pragma unroll
            for (int i = 0; i < 4; ++i)
                #pragma unroll
                for (int j = 0; j < 4; ++j)
                    acc[i][j] += a[i].x * bb[j].x + a[i].y * bb[j].y
                               + a[i].z * bb[j].z + a[i].w * bb[j].w;
        }
        __syncthreads();
        if (kt + 1 < nkt) { COMMIT(nxt); __syncthreads(); }
    }

    #pragma unroll
    for (int j = 0; j < 4; ++j)
        #pragma unroll
        for (int i = 0; i < 4; ++i)
            part[(size_t)(j * 8 + bg) * RS + grow0 + i * 32 + rg] = acc[i][j];
    #undef ISSUE
    #undef COMMIT
}

// ---------------- Kernel 1a: QKV projection (partials) ---------------------
__global__ __launch_bounds__(256) void gemv_qkv(
    const float* __restrict__ x, const float* __restrict__ wq,
    const float* __restrict__ wk, const float* __restrict__ wv,
    float* __restrict__ ws)
{
    const int mt = blockIdx.x >> 3;          // 0..23
    const int ks = blockIdx.x & 7;           // chunk = 256 -> nkt = 8
    const float* W;
    if (mt < 16)      W = wq + (size_t)mt * 128 * HIDDEN;
    else if (mt < 20) W = wk + (size_t)(mt - 16) * 128 * HIDDEN;
    else              W = wv + (size_t)(mt - 20) * 128 * HIDDEN;
    const int k0 = ks * 256;
    float* part = ws + ARENA + (size_t)ks * 32 * 3072;
    gemv_body(W + k0, x + k0, part, 3072, mt * 128, 8);
}

// ---------------- Kernel 1b: reduce partials + RMSNorm + RoPE --------------
__global__ __launch_bounds__(128) void qkv_post(
    const float* __restrict__ position, const float* __restrict__ qnw,
    const float* __restrict__ knw, float* __restrict__ ws)
{
    const int blk = blockIdx.x;
    const int b = blk / 24, h = blk % 24;    // h: 0-15 q, 16-19 k, 20-23 v
    const int d = threadIdx.x, lane = d & 63, wave = d >> 6;
    const int grow = h * 128 + d;

    float v = 0.f;
    #pragma unroll
    for (int s = 0; s < NSPLIT; ++s)
        v += ws[ARENA + (size_t)s * 32 * 3072 + (size_t)b * 3072 + grow];

    if (h >= 20) {
        ws[VBUF + (size_t)(b * NUM_KV + (h - 20)) * HEAD_DIM + d] = v;
        return;
    }

    __shared__ float red[2];
    __shared__ float vl[128];
    vl[d] = v;
    float t2 = v * v;
    #pragma unroll
    for (int off = 32; off; off >>= 1) t2 += __shfl_xor(t2, off);
    if (lane == 0) red[wave] = t2;
    __syncthreads();

    if (d < 64) {
        const float norm = rsqrtf((red[0] + red[1]) * (1.0f / HEAD_DIM) + EPS);
        const float* nw = (h < 16) ? qnw : knw;
        float n1 = vl[d]      * norm * nw[d];
        float n2 = vl[d + 64] * norm * nw[d + 64];
        const float p = position[0];
        float invf = __powf(THETA, -(float)d * (1.0f / 64.0f));
        float f = p * invf, s, c;
        __sincosf(f, &s, &c);
        float* outp = (h < 16)
            ? ws + QBUF + (size_t)(b * NUM_HEADS + h) * HEAD_DIM
            : ws + KBUF + (size_t)(b * NUM_KV + (h - 16)) * HEAD_DIM;
        outp[d]      = n1 * c - n2 * s;
        outp[d + 64] = n2 * c + n1 * s;
    }
}

// ---------------- Kernel 2: flash-decode attention (split over seq) --------
__global__ __launch_bounds__(256) void attn_kernel(
    const float* __restrict__ kcache, const float* __restrict__ vcache,
    const float* __restrict__ position, float* __restrict__ ws)
{
    const int blk = blockIdx.x;         // bk*NSPLIT + split
    const int split = blk & (NSPLIT - 1);
    const int bk = blk >> 3;            // b*4+kv
    const int tid = threadIdx.x, lane = tid & 63, wave = tid >> 6;
    const int half = lane >> 5, li = lane & 31;
    const int b = bk >> 2, kv = bk & 3;
    const int pos = (int)position[0];

    const int chunk = (pos + NSPLIT) / NSPLIT;
    const int s0 = split * chunk;
    const int s1 = min(s0 + chunk, pos + 1);

    const float* qb = ws + QBUF + ((size_t)b * NUM_HEADS + kv * GROUPS) * HEAD_DIM;
    float4 q4[4];
    #pragma unroll
    for (int g = 0; g < 4; ++g)
        q4[g] = ((const float4*)(qb + g * HEAD_DIM))[li];

    const float* kc = kcache + (size_t)bk * MAX_SEQ * HEAD_DIM;
    const float* vc = vcache + (size_t)bk * MAX_SEQ * HEAD_DIM;
    const float* knew = ws + KBUF + (size_t)bk * HEAD_DIM;
    const float* vnew = ws + VBUF + (size_t)bk * HEAD_DIM;

    float m[4], l[4]; float4 acc[4];
    #pragma unroll
    for (int g = 0; g < 4; ++g) {
        m[g] = -1e30f; l[g] = 0.f;
        acc[g] = make_float4(0.f, 0.f, 0.f, 0.f);
    }

    for (int t = s0 + wave * 2 + half; t < s1; t += 16) {
        const int tb = t + 8;
        const bool vb = (tb < s1);
        const int tbc = vb ? tb : t;
        const float4* kpa = (const float4*)((t   == pos) ? knew : kc + (size_t)t   * HEAD_DIM);
        const float4* kpb = (const float4*)((tbc == pos) ? knew : kc + (size_t)tbc * HEAD_DIM);
        const float4* vpa = (const float4*)((t   == pos) ? vnew : vc + (size_t)t   * HEAD_DIM);
        const float4* vpb = (const float4*)((tbc == pos) ? vnew : vc + (size_t)tbc * HEAD_DIM);
        float4 ka = kpa[li], kb = kpb[li];
        float4 va = vpa[li], vb4 = vpb[li];

        float sa[4], sb[4];
        #pragma unroll
        for (int g = 0; g < 4; ++g) {
            sa[g] = q4[g].x * ka.x + q4[g].y * ka.y + q4[g].z * ka.z + q4[g].w * ka.w;
            sb[g] = q4[g].x * kb.x + q4[g].y * kb.y + q4[g].z * kb.z + q4[g].w * kb.w;
        }
        #pragma unroll
        for (int off = 16; off; off >>= 1) {
            #pragma unroll
            for (int g = 0; g < 4; ++g) {
                sa[g] += __shfl_xor(sa[g], off);
                sb[g] += __shfl_xor(sb[g], off);
            }
        }
        #pragma unroll
        for (int g = 0; g < 4; ++g) {
            float sga = sa[g] * SCALE;
            float sgb = vb ? sb[g] * SCALE : -1e30f;
            float mn  = fmaxf(m[g], fmaxf(sga, sgb));
            float alpha = __expf(m[g] - mn);
            float pa = __expf(sga - mn);
            float pb = vb ? __expf(sgb - mn) : 0.f;
            l[g] = l[g] * alpha + pa + pb;
            acc[g].x = acc[g].x * alpha + pa * va.x + pb * vb4.x;
            acc[g].y = acc[g].y * alpha + pa * va.y + pb * vb4.y;
            acc[g].z = acc[g].z * alpha + pa * va.z + pb * vb4.z;
            acc[g].w = acc[g].w * alpha + pa * va.w + pb * vb4.w;
            m[g] = mn;
        }
    }

    __shared__ float sm[8][4], sl[8][4];
    __shared__ float4 sacc[8][4][32];
    const int st = wave * 2 + half;
    #pragma unroll
    for (int g = 0; g < 4; ++g) {
        if (li == 0) { sm[st][g] = m[g]; sl[st][g] = l[g]; }
        sacc[st][g][li] = acc[g];
    }
    __syncthreads();

    float* part = ws + ARENA + (size_t)blk * 4 * 130;
    if (tid < HEAD_DIM) {
        const int d = tid;
        #pragma unroll
        for (int g = 0; g < 4; ++g) {
            float M = -1e30f;
            #pragma unroll
            for (int s = 0; s < 8; ++s) M = fmaxf(M, sm[s][g]);
            float L = 0.f, A = 0.f;
            #pragma unroll
            for (int s = 0; s < 8; ++s) {
                float e = __expf(sm[s][g] - M);
                L += sl[s][g] * e;
                A += ((const float*)&sacc[s][g][0])[d] * e;
            }
            part[g * 130 + d] = A;
            if (d == 0) { part[g * 130 + 128] = M; part[g * 130 + 129] = L; }
        }
    }
}

// ---------------- Kernel 3: combine split partials -> attn_out -------------
__global__ __launch_bounds__(128) void comb_kernel(float* __restrict__ ws)
{
    const int blk = blockIdx.x;         // b*16 + h
    const int b = blk >> 4, h = blk & 15;
    const int kv = h >> 2, g = h & 3;
    const int d = threadIdx.x;
    const float* base = ws + ARENA + ((size_t)(b * NUM_KV + kv) * NSPLIT) * 4 * 130 + g * 130;

    float M = -1e30f;
    #pragma unroll
    for (int s = 0; s < NSPLIT; ++s) M = fmaxf(M, base[s * 520 + 128]);
    float L = 0.f, A = 0.f;
    #pragma unroll
    for (int s = 0; s < NSPLIT; ++s) {
        float e = __expf(base[s * 520 + 128] - M);
        L += base[s * 520 + 129] * e;
        A += base[s * 520 + d] * e;
    }
    ws[AOUT + (size_t)b * HIDDEN + h * HEAD_DIM + d] = A / L;
}

// ---------------- Kernel 4a: output projection (partials) ------------------
__global__ __launch_bounds__(256) void gemv_wo(
    const float* __restrict__ wo, float* __restrict__ ws)
{
    const int mt = blockIdx.x >> 4;          // 0..15
    const int ks = blockIdx.x & 15;          // chunk = 128 -> nkt = 4
    const int k0 = ks * 128;
    float* part = ws + ARENA + (size_t)ks * 32 * 2048;
    gemv_body(wo + (size_t)mt * 128 * HIDDEN + k0, ws + AOUT + k0,
              part, 2048, mt * 128, 4);
}

// ---------------- Kernel 4b: reduce wo partials -> out ---------------------
__global__ __launch_bounds__(256) void ocomb(
    const float* __restrict__ ws, float* __restrict__ out)
{
    const int idx = blockIdx.x * 256 + threadIdx.x;   // 0..16383
    const int b = idx >> 9, r4 = (idx & 511) * 4;
    float4 s = make_float4(0.f, 0.f, 0.f, 0.f);
    #pragma unroll
    for (int k = 0; k < 16; ++k) {
        float4 t = *(const float4*)(ws + ARENA + (size_t)k * 32 * 2048 + (size_t)b * 2048 + r4);
        s.x += t.x; s.y += t.y; s.z += t.z; s.w += t.w;
    }
    *(float4*)(out + (size_t)b * HIDDEN + r4) = s;
}

extern "C" void kernel_launch(void* const* d_in, const int* in_sizes, int n_in,
                              void* d_out, int out_size, void* d_ws, size_t ws_size,
                              hipStream_t stream) {
    const float* x        = (const float*)d_in[0];
    const float* position = (const float*)d_in[1];
    const float* kcache   = (const float*)d_in[3];
    const float* vcache   = (const float*)d_in[4];
    const float* wq       = (const float*)d_in[6];
    const float* wk       = (const float*)d_in[7];
    const float* wv       = (const float*)d_in[8];
    const float* wo       = (const float*)d_in[9];
    const float* qnw      = (const float*)d_in[10];
    const float* knw      = (const float*)d_in[11];
    float* ws  = (float*)d_ws;
    float* out = (float*)d_out;

    gemv_qkv<<<24 * 8, 256, 0, stream>>>(x, wq, wk, wv, ws);
    qkv_post<<<32 * 24, 128, 0, stream>>>(position, qnw, knw, ws);
    attn_kernel<<<32 * NUM_KV * NSPLIT, 256, 0, stream>>>(kcache, vcache, position, ws);
    comb_kernel<<<32 * NUM_HEADS, 128, 0, stream>>>(ws);
    gemv_wo<<<16 * 16, 256, 0, stream>>>(wo, ws);
    ocomb<<<64, 256, 0, stream>>>(ws, out);
}